// Round 2
// baseline (367.192 us; speedup 1.0000x reference)
//
#include <hip/hip_runtime.h>

#define BB 64
#define NN 4096
#define MM 128
#define SCALE 0.25f
#define NCHUNK 32
#define WAVES 4

// One wave handles one (b, n) at a time; lane l owns m = 2l, 2l+1.
// Votes are computed once and reused for both the qk dot and the output
// accumulation. Block = 4 waves, all same b, covering 4*NCHUNK n's.
__global__ __launch_bounds__(256) void caps_fused(const float* __restrict__ x,
                                                  const float* __restrict__ ncv,
                                                  const float* __restrict__ w,
                                                  float* __restrict__ out_acc) {
    const int b    = blockIdx.x & 63;      // b fastest -> concurrent blocks share w slice in L2
    const int grp  = blockIdx.x >> 6;
    const int wave = threadIdx.x >> 6;
    const int lane = threadIdx.x & 63;
    const int m0   = lane * 2;
    const int n_begin = (grp * WAVES + wave) * NCHUNK;

    // ncv[b, m0, :] and ncv[b, m0+1, :]  (k = a*4+d)
    float nc0[16], nc1[16];
    {
        const float4* p0 = (const float4*)(ncv + ((size_t)b * MM + m0) * 16);
        const float4* p1 = (const float4*)(ncv + ((size_t)b * MM + m0 + 1) * 16);
#pragma unroll
        for (int i = 0; i < 4; ++i) {
            float4 t = p0[i];
            nc0[4 * i + 0] = t.x; nc0[4 * i + 1] = t.y; nc0[4 * i + 2] = t.z; nc0[4 * i + 3] = t.w;
            float4 u = p1[i];
            nc1[4 * i + 0] = u.x; nc1[4 * i + 1] = u.y; nc1[4 * i + 2] = u.z; nc1[4 * i + 3] = u.w;
        }
    }

    float oa0[16], oa1[16];
#pragma unroll
    for (int k = 0; k < 16; ++k) { oa0[k] = 0.0f; oa1[k] = 0.0f; }

    for (int n = n_begin; n < n_begin + NCHUNK; ++n) {
        // pose[b,n,a,x] -> pr[a*4+x]  (wave-uniform address, broadcast)
        float pr[16];
        {
            const float4* pp = (const float4*)(x + ((size_t)b * NN + n) * 16);
#pragma unroll
            for (int i = 0; i < 4; ++i) {
                float4 t = pp[i];
                pr[4 * i + 0] = t.x; pr[4 * i + 1] = t.y; pr[4 * i + 2] = t.z; pr[4 * i + 3] = t.w;
            }
        }
        // w[n, x, d, m0:m0+2]  k = x*4+d ; coalesced float2 across lanes (m stride-1)
        float2 wv[16];
        {
            const float* wbase = w + (size_t)n * 2048 + m0;
#pragma unroll
            for (int k = 0; k < 16; ++k) wv[k] = *(const float2*)(wbase + k * 128);
        }
        // votes: v[a*4+d] = sum_x pose[a,x] * w[x,d]
        float v0[16], v1[16];
#pragma unroll
        for (int a = 0; a < 4; ++a) {
#pragma unroll
            for (int d = 0; d < 4; ++d) {
                float s0 = 0.0f, s1 = 0.0f;
#pragma unroll
                for (int xx = 0; xx < 4; ++xx) {
                    s0 = fmaf(pr[a * 4 + xx], wv[xx * 4 + d].x, s0);
                    s1 = fmaf(pr[a * 4 + xx], wv[xx * 4 + d].y, s1);
                }
                v0[a * 4 + d] = s0;
                v1[a * 4 + d] = s1;
            }
        }
        // qk = SCALE * <vote, ncv>
        float qk0 = 0.0f, qk1 = 0.0f;
#pragma unroll
        for (int k = 0; k < 16; ++k) {
            qk0 = fmaf(v0[k], nc0[k], qk0);
            qk1 = fmaf(v1[k], nc1[k], qk1);
        }
        qk0 *= SCALE; qk1 *= SCALE;

        // softmax over the 128 m's held by this wave (2 per lane);
        // the reference's post-softmax renorm (/= sum+1e-10) is a fp32 no-op.
        float mx = fmaxf(qk0, qk1);
#pragma unroll
        for (int off = 32; off; off >>= 1) mx = fmaxf(mx, __shfl_xor(mx, off));
        float p0 = __expf(qk0 - mx), p1 = __expf(qk1 - mx);
        float s = p0 + p1;
#pragma unroll
        for (int off = 32; off; off >>= 1) s += __shfl_xor(s, off);
        float sinv = 1.0f / s;
        float r0 = p0 * sinv, r1 = p1 * sinv;

        // accumulate out partial: oa += r * vote
#pragma unroll
        for (int k = 0; k < 16; ++k) {
            oa0[k] = fmaf(r0, v0[k], oa0[k]);
            oa1[k] = fmaf(r1, v1[k], oa1[k]);
        }
    }

    // block-level combine (4 waves, same b) then one atomicAdd per element
    __shared__ float lacc[MM * 16];
    for (int i = threadIdx.x; i < MM * 16; i += 256) lacc[i] = 0.0f;
    __syncthreads();
#pragma unroll
    for (int k = 0; k < 16; ++k) {
        atomicAdd(&lacc[m0 * 16 + k], oa0[k]);
        atomicAdd(&lacc[(m0 + 1) * 16 + k], oa1[k]);
    }
    __syncthreads();
    float* gout = out_acc + (size_t)b * (MM * 16);
    for (int i = threadIdx.x; i < MM * 16; i += 256) atomicAdd(&gout[i], lacc[i]);
}

// LayerNorm over last dim (16) of acc[b, m, 16] -> out
__global__ __launch_bounds__(256) void caps_ln(const float* __restrict__ acc,
                                               const float* __restrict__ gamma,
                                               const float* __restrict__ beta,
                                               float* __restrict__ out) {
    int r = blockIdx.x * blockDim.x + threadIdx.x;
    if (r >= BB * MM) return;
    float v[16];
    const float4* p = (const float4*)(acc + (size_t)r * 16);
#pragma unroll
    for (int i = 0; i < 4; ++i) {
        float4 t = p[i];
        v[4 * i + 0] = t.x; v[4 * i + 1] = t.y; v[4 * i + 2] = t.z; v[4 * i + 3] = t.w;
    }
    float mu = 0.0f;
#pragma unroll
    for (int k = 0; k < 16; ++k) mu += v[k];
    mu *= (1.0f / 16.0f);
    float var = 0.0f;
#pragma unroll
    for (int k = 0; k < 16; ++k) {
        float d = v[k] - mu;
        var = fmaf(d, d, var);
    }
    var *= (1.0f / 16.0f);
    float rs = rsqrtf(var + 1e-5f);
    float4* o = (float4*)(out + (size_t)r * 16);
#pragma unroll
    for (int i = 0; i < 4; ++i) {
        float4 t;
        t.x = (v[4 * i + 0] - mu) * rs * gamma[4 * i + 0] + beta[4 * i + 0];
        t.y = (v[4 * i + 1] - mu) * rs * gamma[4 * i + 1] + beta[4 * i + 1];
        t.z = (v[4 * i + 2] - mu) * rs * gamma[4 * i + 2] + beta[4 * i + 2];
        t.w = (v[4 * i + 3] - mu) * rs * gamma[4 * i + 3] + beta[4 * i + 3];
        o[i] = t;
    }
}

extern "C" void kernel_launch(void* const* d_in, const int* in_sizes, int n_in,
                              void* d_out, int out_size, void* d_ws, size_t ws_size,
                              hipStream_t stream) {
    const float* x     = (const float*)d_in[0];
    const float* ncv   = (const float*)d_in[1];
    const float* w     = (const float*)d_in[2];
    const float* gamma = (const float*)d_in[3];
    const float* beta  = (const float*)d_in[4];
    // d_in[5] = num_iter (unused; reference does a single routing pass)
    float* out = (float*)d_out;
    float* acc = (float*)d_ws;   // BB*MM*16 fp32 accumulator = 512 KiB

    hipMemsetAsync(acc, 0, (size_t)BB * MM * 16 * sizeof(float), stream);

    dim3 grid(BB * (NN / (WAVES * NCHUNK)));   // 64 * 32 = 2048 blocks
    caps_fused<<<grid, 256, 0, stream>>>(x, ncv, w, acc);

    caps_ln<<<(BB * MM + 255) / 256, 256, 0, stream>>>(acc, gamma, beta, out);
}